// Round 1
// baseline (286.364 us; speedup 1.0000x reference)
//
#include <hip/hip_runtime.h>

#define RR   80      // max radius (TRUNCATE * MAX_SIGMA + 0.5)
#define WDIM 256     // H == W == 256
#define NSAMP 512
#define BH   16      // output rows per block along blur axis
#define UCH  8       // tap chunk (weights kept in registers)

__device__ __forceinline__ int reflect(int q) {
    // symmetric padding, single reflection valid since RR <= WDIM
    q = (q < 0) ? (-q - 1) : q;
    return (q >= WDIM) ? (2 * WDIM - 1 - q) : q;
}

// Compute normalized per-sample weights into wl[192] (zero-padded outside [0,160]).
// Returns radius. Must be called by all 256 threads (contains __syncthreads).
__device__ __forceinline__ int make_weights(int b, const float* __restrict__ sigmas,
                                            const int* __restrict__ steps,
                                            float* wl, float* red) {
    int t = threadIdx.x;
    float sigma = sigmas[steps[b]];
    float radf = floorf(4.0f * sigma + 0.5f);
    if (t < 192) {
        float w = 0.0f;
        if (t < 161) {
            float off = (float)(t - RR);
            if (fabsf(off) <= radf) {
                float z = off / sigma;
                w = expf(-0.5f * z * z);
            }
        }
        wl[t] = w;
    }
    __syncthreads();
    if (t < 64) {
        float s = wl[t] + wl[t + 64] + wl[t + 128];
        #pragma unroll
        for (int o = 32; o > 0; o >>= 1) s += __shfl_down(s, o);
        if (t == 0) red[0] = 1.0f / s;
    }
    __syncthreads();
    float rs = red[0];
    if (t < 161) wl[t] *= rs;
    __syncthreads();
    return (int)radf;
}

// Blur along the second-to-last index of in[b][r][c]; if TOUT, write out[b][c][r]
// (transposed), else out[b][r][c]. Applying the TOUT version twice gives
// horizontal(vertical(x)) in normal orientation.
template <bool TOUT>
__global__ __launch_bounds__(256) void vblur(const float* __restrict__ in,
                                             float* __restrict__ out,
                                             const float* __restrict__ sigmas,
                                             const int* __restrict__ steps) {
    __shared__ float wl[192];
    __shared__ float red[1];
    int bid = blockIdx.x;
    int b   = bid >> 4;          // 16 chunks of BH rows per sample
    int i0  = (bid & 15) * BH;
    int rad = make_weights(b, sigmas, steps, wl, red);
    int j = threadIdx.x;
    const float* inb = in + (size_t)b * WDIM * WDIM;

    float acc[BH];
    #pragma unroll
    for (int ii = 0; ii < BH; ++ii) acc[ii] = 0.0f;

    int nc = (2 * rad + UCH) / UCH;   // ceil((2*rad+1)/UCH)
    int ubase = -rad;
    for (int c = 0; c < nc; ++c, ubase += UCH) {
        float wreg[UCH];
        #pragma unroll
        for (int t = 0; t < UCH; ++t) wreg[t] = wl[RR + ubase + t];  // broadcast reads
        float vwin[BH + UCH - 1];
        #pragma unroll
        for (int s = 0; s < BH + UCH - 1; ++s) {
            int rr = reflect(i0 + ubase + s);
            vwin[s] = inb[rr * WDIM + j];   // coalesced across lanes
        }
        #pragma unroll
        for (int ii = 0; ii < BH; ++ii) {
            #pragma unroll
            for (int t = 0; t < UCH; ++t)
                acc[ii] = fmaf(wreg[t], vwin[ii + t], acc[ii]);
        }
    }

    if (TOUT) {
        float* ob = out + ((size_t)b * WDIM + j) * WDIM + i0;  // 64B aligned (i0 % 16 == 0)
        float4* o4 = (float4*)ob;
        #pragma unroll
        for (int q = 0; q < BH / 4; ++q)
            o4[q] = make_float4(acc[4 * q], acc[4 * q + 1], acc[4 * q + 2], acc[4 * q + 3]);
    } else {
        #pragma unroll
        for (int ii = 0; ii < BH; ++ii)
            out[((size_t)b * WDIM + (i0 + ii)) * WDIM + j] = acc[ii];
    }
}

// Fallback horizontal pass (in-place, row-local): only used if ws_size is too small.
__global__ __launch_bounds__(256) void hblur_inplace(float* __restrict__ buf,
                                                     const float* __restrict__ sigmas,
                                                     const int* __restrict__ steps) {
    __shared__ float wl[192];
    __shared__ float red[1];
    __shared__ float rp[WDIM + 2 * RR];
    int bid = blockIdx.x;
    int b = bid >> 8;
    int i = bid & 255;
    float* row = buf + ((size_t)b * WDIM + i) * WDIM;
    int t = threadIdx.x;
    // stage padded row (reads happen before make_weights' first sync barrier is fine:
    // do it first, make_weights syncs afterwards)
    for (int s = t; s < WDIM + 2 * RR; s += 256) rp[s] = row[reflect(s - RR)];
    int rad = make_weights(b, sigmas, steps, wl, red);  // includes __syncthreads
    float acc = 0.0f;
    for (int u = -rad; u <= rad; ++u) acc = fmaf(wl[RR + u], rp[RR + t + u], acc);
    row[t] = acc;
}

extern "C" void kernel_launch(void* const* d_in, const int* in_sizes, int n_in,
                              void* d_out, int out_size, void* d_ws, size_t ws_size,
                              hipStream_t stream) {
    const float* x     = (const float*)d_in[0];
    const float* sig   = (const float*)d_in[1];
    const int*   steps = (const int*)d_in[2];
    float* out = (float*)d_out;

    const size_t tmp_bytes = (size_t)NSAMP * WDIM * WDIM * sizeof(float);
    const int nblk = NSAMP * (WDIM / BH);   // 8192

    if (ws_size >= tmp_bytes) {
        float* tmp = (float*)d_ws;
        vblur<true><<<nblk, 256, 0, stream>>>(x, tmp, sig, steps);
        vblur<true><<<nblk, 256, 0, stream>>>(tmp, out, sig, steps);
    } else {
        vblur<false><<<nblk, 256, 0, stream>>>(x, out, sig, steps);
        hblur_inplace<<<NSAMP * WDIM, 256, 0, stream>>>(out, sig, steps);
    }
}